// Round 12
// baseline (674.269 us; speedup 1.0000x reference)
//
#include <hip/hip_runtime.h>
#include <hip/hip_fp16.h>
#include <math.h>

// ---------------------------------------------------------------------------
// TAGConv x2 + linear + sigmoid, 500k nodes / 4M edges.
// Round 12: build_kernel scatter split into 8 lockstep passes over 256-node
//           ld-ranges -> per-pass write slice ~12 KB stays in L2 until fully
//           written (kills the 166 MB write amplification). TB 512.
// Scaled-state propagation z_k = dinv .* h_k (fp16 state); MFMA epilogue.
// ---------------------------------------------------------------------------

#define TB 256
#define TBLD 512
#define TBIN 512
#define BSHIFT 11
#define BW 2048             // nodes per bucket
#define CAPB 17408          // binBuf cap (raw recs; mean 16384, ~8 sigma)
#define CAP 26624           // payload cap per bucket (8-padded; mean ~23.6k)
#define BIN_CHUNK 8192      // edges per block in bin_kernel
#define WQ 8191.0f          // 13-bit weight quantization

typedef _Float16 half8 __attribute__((ext_vector_type(8)));
typedef float floatx4 __attribute__((ext_vector_type(4)));

// Phase 1: one-pass binning, register-staged dst. rec: {src|ld<<19, w-bits}
__global__ __launch_bounds__(TBIN) void bin_kernel(
        const int* __restrict__ src, const int* __restrict__ dst,
        const float* __restrict__ w, int* __restrict__ binCount,
        uint2* __restrict__ binBuf, int E, int NB) {
    __shared__ int bcnt[256];
    __shared__ int bbase[256];
    for (int i = threadIdx.x; i < 256; i += TBIN) bcnt[i] = 0;
    __syncthreads();

    int base = blockIdx.x * BIN_CHUNK;
    int d[16];
#pragma unroll
    for (int j = 0; j < 16; j++) {
        int e = base + threadIdx.x + j * TBIN;
        d[j] = (e < E) ? dst[e] : -1;
        if (d[j] >= 0) atomicAdd(&bcnt[d[j] >> BSHIFT], 1);
    }
    __syncthreads();
    for (int i = threadIdx.x; i < NB; i += TBIN) {
        int c = bcnt[i];
        bbase[i] = c ? atomicAdd(&binCount[i], c) : 0;
        bcnt[i] = 0;   // reuse as local cursor
    }
    __syncthreads();
#pragma unroll
    for (int j = 0; j < 16; j++) {
        if (d[j] >= 0) {
            int e = base + threadIdx.x + j * TBIN;
            int b = d[j] >> BSHIFT;
            int off = bbase[b] + atomicAdd(&bcnt[b], 1);
            if (off < CAPB) {
                binBuf[(size_t)b * CAPB + off] =
                    make_uint2((unsigned)src[e] | ((unsigned)(d[j] & (BW - 1)) << 19),
                               __float_as_uint(w[e]));
            }
        }
    }
}

// Phase 2: one block per bucket -> packed CSR payload (src|q<<19) with
// 8-padded per-node slots (pad recs = 0), seg = (start>>3) | ngroups<<16,
// dinv2, rdinv, z0 = dinv.*x (fp16). Scatter in 8 lockstep 256-node passes.
__global__ __launch_bounds__(TBLD) void build_kernel(
        const int* __restrict__ binCount, const uint2* __restrict__ binBuf,
        unsigned* __restrict__ payload, int* __restrict__ seg,
        float* __restrict__ dinv2, float* __restrict__ rdinv,
        const float* __restrict__ x, __half2* __restrict__ z0,
        int N, int NB) {
    __shared__ int   cnt[BW];
    __shared__ float wsum[BW];
    __shared__ int   start[BW];
    __shared__ int   cur[BW];
    __shared__ int   tmp[TBLD];
    int b = blockIdx.x;
    int nBase = b << BSHIFT;
    int nCount = min(BW, N - nBase);
    int m = min(binCount[b], CAPB);

    for (int i = threadIdx.x; i < BW; i += TBLD) { cnt[i] = 0; wsum[i] = 0.0f; }
    __syncthreads();

    const uint2* recs = binBuf + (size_t)b * CAPB;
    for (int i = threadIdx.x; i < m; i += TBLD) {
        uint2 r = recs[i];
        int ld = r.x >> 19;
        atomicAdd(&cnt[ld], 1);
        atomicAdd(&wsum[ld], __uint_as_float(r.y));
    }
    __syncthreads();

    // exclusive scan of 8-padded counts, 4 elems/thread
    int b4 = threadIdx.x * 4;
    int c[4], s = 0;
#pragma unroll
    for (int j = 0; j < 4; j++) { c[j] = (cnt[b4 + j] + 7) & ~7; s += c[j]; }
    tmp[threadIdx.x] = s;
    __syncthreads();
    for (int off = 1; off < TBLD; off <<= 1) {
        int t = (threadIdx.x >= off) ? tmp[threadIdx.x - off] : 0;
        __syncthreads();
        tmp[threadIdx.x] += t;
        __syncthreads();
    }
    int run = tmp[threadIdx.x] - s;
#pragma unroll
    for (int j = 0; j < 4; j++) { start[b4 + j] = run; run += c[j]; }
    __syncthreads();

    size_t pbase = (size_t)b * CAP;
    for (int i = threadIdx.x; i < BW; i += TBLD) cur[i] = start[i];
    for (int i = threadIdx.x; i < nCount; i += TBLD) {
        int n = nBase + i;
        int cc = cnt[i];
        int st = start[i];
        int ng = (cc + 7) >> 3;
        // defensive clamp (astronomically unlikely)
        if (st >= CAP) { ng = 0; }
        else if (st + 8 * ng > CAP) { ng = (CAP - st) >> 3; }
        seg[n] = (st >> 3) | (ng << 16);
        float dsum = wsum[i];
        float di = (dsum > 0.0f) ? rsqrtf(dsum) : 0.0f;
        dinv2[n] = di * di;
        rdinv[n] = dsum * di;            // sqrt(deg), 0 if deg==0
        float2 xv = reinterpret_cast<const float2*>(x)[n];
        z0[n] = __float22half2_rn(make_float2(di * xv.x, di * xv.y));
    }
    __syncthreads();

    // scatter in 8 passes over 256-node ld ranges (temporal write locality)
    for (int t = 0; t < 8; t++) {
        int lo = t << 8, hi = lo + 256;
        for (int i = threadIdx.x; i < m; i += TBLD) {
            uint2 r = recs[i];
            int ld = r.x >> 19;
            if (ld >= lo && ld < hi) {
                int pos = atomicAdd(&cur[ld], 1);
                unsigned q = (unsigned)__float2int_rn(__uint_as_float(r.y) * WQ);
                if (pos < CAP) payload[pbase + pos] = (r.x & 0x7FFFFu) | (q << 19);
            }
        }
        // pad fill for this node range (lines still hot)
        if (threadIdx.x < 256) {
            int i = lo + threadIdx.x;
            if (i < nCount) {
                int cc = cnt[i];
                int st = start[i];
                int ng = (cc + 7) >> 3;
                if (st >= CAP) ng = 0;
                else if (st + 8 * ng > CAP) ng = (CAP - st) >> 3;
                for (int j = cc; j < 8 * ng; j++) payload[pbase + st + j] = 0;
            }
        }
        __syncthreads();
    }
}

// ---- gather helpers: full groups of 8, payload 16B-aligned, no masks ------

__device__ __forceinline__ void gacc2m(const unsigned* __restrict__ payload,
                                       const __half2* __restrict__ zin,
                                       int beg, int ng, float& ax, float& ay) {
    for (int g = 0; g < ng; g++, beg += 8) {
        uint4 r0 = *reinterpret_cast<const uint4*>(payload + beg);
        uint4 r1 = *reinterpret_cast<const uint4*>(payload + beg + 4);
        unsigned r[8] = {r0.x, r0.y, r0.z, r0.w, r1.x, r1.y, r1.z, r1.w};
        __half2 v[8];
#pragma unroll
        for (int j = 0; j < 8; j++) v[j] = zin[r[j] & 0x7FFFFu];
#pragma unroll
        for (int j = 0; j < 8; j++) {
            float wv = (float)(r[j] >> 19) * (1.0f / WQ);
            float2 f = __half22float2(v[j]);
            ax += wv * f.x;
            ay += wv * f.y;
        }
    }
}

// C=4 (quarter-row); ubase = uin + 4*quarter.
__device__ __forceinline__ void gacc4(const unsigned* __restrict__ payload,
                                      const __half* __restrict__ ubase,
                                      int beg, int ng, float* __restrict__ h) {
    for (int g = 0; g < ng; g++, beg += 8) {
        uint4 r0 = *reinterpret_cast<const uint4*>(payload + beg);
        uint4 r1 = *reinterpret_cast<const uint4*>(payload + beg + 4);
        unsigned r[8] = {r0.x, r0.y, r0.z, r0.w, r1.x, r1.y, r1.z, r1.w};
        float2 a[8];
#pragma unroll
        for (int j = 0; j < 8; j++)
            a[j] = *reinterpret_cast<const float2*>(ubase + 16LL * (int)(r[j] & 0x7FFFFu));
#pragma unroll
        for (int j = 0; j < 8; j++) {
            float wv = (float)(r[j] >> 19) * (1.0f / WQ);
            const __half2* hp = reinterpret_cast<const __half2*>(&a[j]);
            float2 v0 = __half22float2(hp[0]);
            float2 v1 = __half22float2(hp[1]);
            h[0] += wv * v0.x;
            h[1] += wv * v0.y;
            h[2] += wv * v1.x;
            h[3] += wv * v1.y;
        }
    }
}

// ----------------------------------------------------------------------------

// z_k[n] = dinv2[n] * sum w * z_{k-1}[src]   (C=2, fp16 state), k=1..3
__global__ void hop2_kernel(const int* __restrict__ seg, const unsigned* __restrict__ payload,
                            const __half2* __restrict__ zin, const float* __restrict__ dinv2,
                            __half2* __restrict__ zout, int N) {
    int n = blockIdx.x * TB + threadIdx.x;
    if (n >= N) return;
    int sp = seg[n];
    int beg = (n >> BSHIFT) * CAP + ((sp & 0xFFFF) << 3);
    int ng = sp >> 16;
    float ax = 0.0f, ay = 0.0f;
    gacc2m(payload, zin, beg, ng, ax, ay);
    float sc = dinv2[n];
    zout[n] = __float22half2_rn(make_float2(ax * sc, ay * sc));
}

// Fused hop2 k=4 + conv1 epilogue
__global__ void hop2_final_kernel(const int* __restrict__ seg, const unsigned* __restrict__ payload,
                                  const __half2* __restrict__ zbuf,   // z0..z3
                                  const float* __restrict__ x,
                                  const float* __restrict__ rdinv, const float* __restrict__ dinv2,
                                  const float* __restrict__ W1, const float* __restrict__ b1,
                                  __half* __restrict__ g0, __half* __restrict__ u0, int N) {
    __shared__ float Ws[160];
    __shared__ float bs[16];
    for (int i = threadIdx.x; i < 160; i += blockDim.x) Ws[i] = W1[i];
    if (threadIdx.x < 16) bs[threadIdx.x] = b1[threadIdx.x];
    __syncthreads();

    int n = blockIdx.x * TB + threadIdx.x;
    if (n >= N) return;

    int sp = seg[n];
    int beg = (n >> BSHIFT) * CAP + ((sp & 0xFFFF) << 3);
    int ng = sp >> 16;
    const __half2* z3 = zbuf + (size_t)3 * N;
    float ax = 0.0f, ay = 0.0f;
    gacc2m(payload, z3, beg, ng, ax, ay);
    float sc = dinv2[n];
    float rd = rdinv[n];

    float coeff[10];
    {
        float2 v = reinterpret_cast<const float2*>(x)[n];
        coeff[0] = v.x; coeff[1] = v.y;
    }
#pragma unroll
    for (int k = 1; k <= 3; k++) {
        float2 v = __half22float2(zbuf[(size_t)k * N + n]);
        coeff[2 * k + 0] = rd * v.x;
        coeff[2 * k + 1] = rd * v.y;
    }
    coeff[8] = rd * sc * ax;
    coeff[9] = rd * sc * ay;

    float o[16];
#pragma unroll
    for (int c = 0; c < 16; c++) o[c] = bs[c];
#pragma unroll
    for (int j = 0; j < 10; j++) {
        float cf = coeff[j];
#pragma unroll
        for (int c = 0; c < 16; c++) o[c] += cf * Ws[j * 16 + c];
    }
#pragma unroll
    for (int c = 0; c < 16; c++) o[c] = fmaxf(o[c], 0.0f);

    float di = sc * rd;   // = dinv (0 for deg-0 nodes)

    __half2 gp[8], up[8];
#pragma unroll
    for (int q = 0; q < 8; q++) {
        gp[q] = __float22half2_rn(make_float2(o[2 * q], o[2 * q + 1]));
        up[q] = __float22half2_rn(make_float2(di * o[2 * q], di * o[2 * q + 1]));
    }
    float4* gw = reinterpret_cast<float4*>(g0 + 16LL * n);
    gw[0] = *reinterpret_cast<float4*>(&gp[0]);
    gw[1] = *reinterpret_cast<float4*>(&gp[4]);
    float4* uw = reinterpret_cast<float4*>(u0 + 16LL * n);
    uw[0] = *reinterpret_cast<float4*>(&up[0]);
    uw[1] = *reinterpret_cast<float4*>(&up[4]);
}

// u_k = dinv2 * sum w * u_{k-1}[src]; 4 threads per node (4 channels each)
__global__ void hop16_kernel(const int* __restrict__ seg, const unsigned* __restrict__ payload,
                             const __half* __restrict__ uin, const float* __restrict__ dinv2,
                             __half* __restrict__ uout, int N) {
    int gid = blockIdx.x * TB + threadIdx.x;
    int n = gid >> 2, quarter = gid & 3;
    if (n >= N) return;
    int sp = seg[n];
    int beg = (n >> BSHIFT) * CAP + ((sp & 0xFFFF) << 3);
    int ng = sp >> 16;

    float h[4] = {0.0f, 0.0f, 0.0f, 0.0f};
    gacc4(payload, uin + 4 * quarter, beg, ng, h);

    float sc = dinv2[n];
    __half2 p[2];
    p[0] = __float22half2_rn(make_float2(h[0] * sc, h[1] * sc));
    p[1] = __float22half2_rn(make_float2(h[2] * sc, h[3] * sc));
    *reinterpret_cast<float2*>(uout + 16LL * n + 4 * quarter) = *reinterpret_cast<float2*>(&p[0]);
}

// Fused hop16 k=4 + conv2 epilogue via MFMA + endLinear + sigmoid.
// Wave = 16 nodes x 4 quads; node=lane&15, quarter=lane>>4.
__global__ void hop16_final_kernel(const int* __restrict__ seg, const unsigned* __restrict__ payload,
                                   const __half* __restrict__ g0, const __half* __restrict__ ubuf,
                                   const float* __restrict__ rdinv, const float* __restrict__ dinv2,
                                   const float* __restrict__ W2, const float* __restrict__ b2,
                                   const float* __restrict__ Wend, float* __restrict__ out, int N) {
    int lane = threadIdx.x & 63;
    int wave = threadIdx.x >> 6;
    int q = lane >> 4;           // quad -> K-chunk
    int nn = lane & 15;          // node row m / output column n
    int node_base = (blockIdx.x * 4 + wave) * 16;
    int node = node_base + nn;
    int nodec = min(node, N - 1);

    // B fragments: lane supplies B[K=32t+8q+i][n=nn] from W2 (fp32->fp16)
    half8 bf[3];
#pragma unroll
    for (int t = 0; t < 3; t++) {
        half8 bv;
#pragma unroll
        for (int i = 0; i < 8; i++) {
            int K = 32 * t + 8 * q + i;
            K = (K < 80) ? K : 79;          // pad rows never used (A=0 there)
            bv[i] = (_Float16)W2[K * 16 + nn];
        }
        bf[t] = bv;
    }
    float bsv = b2[nn];
    float wev = Wend[nn];

    // gather k=4 term: h = quarter q (channels 4q..4q+3) of node's u4 row
    int sp = seg[nodec];
    int beg = (nodec >> BSHIFT) * CAP + ((sp & 0xFFFF) << 3);
    int ng = sp >> 16;
    const __half* u3 = ubuf + (size_t)3 * 16 * N;
    float h[4] = {0.0f, 0.0f, 0.0f, 0.0f};
    gacc4(payload, u3 + 4 * q, beg, ng, h);

    float rd = rdinv[nodec];
    float sc = dinv2[nodec];

    // A fragment t=0: q0,q1 -> g0 (raw); q2,q3 -> u1 (x rd)
    const __half* a0p = ((q < 2) ? g0 : (ubuf + (size_t)16 * N)) + 16LL * nodec + 8 * (q & 1);
    half8 a0 = *reinterpret_cast<const half8*>(a0p);
    a0 = a0 * ((q >= 2) ? (_Float16)rd : (_Float16)1.0f);

    // A fragment t=1: q0,q1 -> u2; q2,q3 -> u3 (all x rd)
    const __half* a1p = ((q < 2) ? (ubuf + (size_t)2 * 16 * N) : (ubuf + (size_t)3 * 16 * N))
                        + 16LL * nodec + 8 * (q & 1);
    half8 a1 = *reinterpret_cast<const half8*>(a1p);
    a1 = a1 * (_Float16)rd;

    // A fragment t=2: q0,q1 -> h (x rd*sc) via shfl repack; q2,q3 -> zero pad
    float s4 = rd * sc;
    __half2 hh0 = __floats2half2_rn(h[0] * s4, h[1] * s4);
    __half2 hh1 = __floats2half2_rn(h[2] * s4, h[3] * s4);
    int p0, p1;
    p0 = *reinterpret_cast<int*>(&hh0);
    p1 = *reinterpret_cast<int*>(&hh1);
    int srcA = (nn + (q << 5)) & 63;   // q0: quarters 0,1 ; q1: quarters 2,3
    int srcB = (srcA + 16) & 63;
    int lo0 = __shfl(p0, srcA, 64);
    int lo1 = __shfl(p1, srcA, 64);
    int hi0 = __shfl(p0, srcB, 64);
    int hi1 = __shfl(p1, srcB, 64);
    if (q >= 2) { lo0 = 0; lo1 = 0; hi0 = 0; hi1 = 0; }
    union { half8 v; int u[4]; } a2;
    a2.u[0] = lo0; a2.u[1] = lo1; a2.u[2] = hi0; a2.u[3] = hi1;

    floatx4 acc = {bsv, bsv, bsv, bsv};
    acc = __builtin_amdgcn_mfma_f32_16x16x32_f16(a0, bf[0], acc, 0, 0, 0);
    acc = __builtin_amdgcn_mfma_f32_16x16x32_f16(a1, bf[1], acc, 0, 0, 0);
    acc = __builtin_amdgcn_mfma_f32_16x16x32_f16(a2.v, bf[2], acc, 0, 0, 0);

    // D[m = q*4+reg][n = nn]: relu, dot with Wend over n, sigmoid, store
    float svals[4];
#pragma unroll
    for (int r = 0; r < 4; r++) {
        float o = fmaxf(acc[r], 0.0f) * wev;
        o += __shfl_xor(o, 1, 64);
        o += __shfl_xor(o, 2, 64);
        o += __shfl_xor(o, 4, 64);
        o += __shfl_xor(o, 8, 64);
        svals[r] = o;
    }
    if (nn == 0) {
#pragma unroll
        for (int r = 0; r < 4; r++) {
            int on = node_base + q * 4 + r;
            if (on < N) out[on] = 1.0f / (1.0f + __expf(-svals[r]));
        }
    }
}

extern "C" void kernel_launch(void* const* d_in, const int* in_sizes, int n_in,
                              void* d_out, int out_size, void* d_ws, size_t ws_size,
                              hipStream_t stream) {
    const float* x    = (const float*)d_in[0];
    const int*   ei   = (const int*)d_in[1];
    const float* w    = (const float*)d_in[2];
    const float* W1   = (const float*)d_in[3];
    const float* b1   = (const float*)d_in[4];
    const float* W2   = (const float*)d_in[5];
    const float* b2   = (const float*)d_in[6];
    const float* Wend = (const float*)d_in[7];
    float* out = (float*)d_out;

    const int N = in_sizes[0] / 2;   // 500000
    const int E = in_sizes[2];       // 4000000
    const int NB = (N + BW - 1) / BW;  // 245

    const int* src = ei;
    const int* dst = ei + E;

    // workspace layout: binCount 4KB | payload 26.1MB | seg 2MB | dinv2 2MB |
    // rdinv 2MB | zbuf 8MB (z0..z3) | g0 16MB | ubuf 64MB (u0..u3);
    // binBuf (34.1MB) aliased over u1..u3 (48MB; dead after build)
    int*      binCount = (int*)d_ws;
    unsigned* payload  = (unsigned*)(binCount + 1024);
    int*      seg      = (int*)(payload + (size_t)NB * CAP);
    float*    dinv2    = (float*)(seg + N);
    float*    rdinv    = dinv2 + N;
    __half2*  zbuf     = (__half2*)(rdinv + N);
    __half*   g0       = (__half*)(zbuf + (size_t)4 * N);
    __half*   ubuf     = g0 + (size_t)16 * N;
    uint2*    binBuf   = (uint2*)(ubuf + (size_t)16 * N);   // over u1..u3

    const int gE_bin = (E + BIN_CHUNK - 1) / BIN_CHUNK;   // 489
    const int gN   = (N + TB - 1) / TB;                   // 1954
    const int gN4  = (4 * N + TB - 1) / TB;               // 7813
    const int gFin = (N + 63) / 64;                       // 7813 (64 nodes/block)

    hipMemsetAsync(binCount, 0, 1024 * sizeof(int), stream);

    // CSR build
    bin_kernel<<<gE_bin, TBIN, 0, stream>>>(src, dst, w, binCount, binBuf, E, NB);
    build_kernel<<<NB, TBLD, 0, stream>>>(binCount, binBuf, payload, seg, dinv2, rdinv, x, zbuf, N, NB);

    // conv1 hops (C=2): z1..z3, then fused z4+epilogue
    for (int k = 1; k <= 3; k++) {
        hop2_kernel<<<gN, TB, 0, stream>>>(seg, payload, zbuf + (size_t)(k - 1) * N,
                                           dinv2, zbuf + (size_t)k * N, N);
    }
    hop2_final_kernel<<<gN, TB, 0, stream>>>(seg, payload, zbuf, x, rdinv, dinv2,
                                             W1, b1, g0, ubuf, N);

    // conv2 hops (C=16): u1..u3 (4 thr/node), then fused u4+MFMA epilogue
    for (int k = 1; k <= 3; k++) {
        hop16_kernel<<<gN4, TB, 0, stream>>>(seg, payload, ubuf + (size_t)(k - 1) * 16 * N,
                                             dinv2, ubuf + (size_t)k * 16 * N, N);
    }
    hop16_final_kernel<<<gFin, TB, 0, stream>>>(seg, payload, g0, ubuf, rdinv, dinv2,
                                                W2, b2, Wend, out, N);
}

// Round 13
// 559.093 us; speedup vs baseline: 1.2060x; 1.2060x over previous
//
#include <hip/hip_runtime.h>
#include <hip/hip_fp16.h>
#include <math.h>

// ---------------------------------------------------------------------------
// TAGConv x2 + linear + sigmoid, 500k nodes / 4M edges.
// Round 13: build_kernel uses an LDS counting-sort index (ord[pos]=rec idx,
//           2B entries, two node-halves) so payload is written as ONE
//           coalesced stream (clean full-line writebacks) while the random
//           access moves to L2-resident recs reads. TBLD=1024.
// Scaled-state propagation z_k = dinv .* h_k (fp16 state); MFMA epilogue.
// ---------------------------------------------------------------------------

#define TB 256
#define TBLD 1024
#define TBIN 512
#define BSHIFT 11
#define BW 2048             // nodes per bucket
#define CAPB 17408          // binBuf cap (raw recs; mean 16384, ~8 sigma)
#define CAP 26624           // payload cap per bucket (8-padded; mean ~23.6k)
#define HALF_CAP 13312      // ord staging per node-half (mean ~11.8k, ~13 sigma)
#define BIN_CHUNK 8192      // edges per block in bin_kernel
#define WQ 8191.0f          // 13-bit weight quantization

typedef _Float16 half8 __attribute__((ext_vector_type(8)));
typedef float floatx4 __attribute__((ext_vector_type(4)));

// Phase 1: one-pass binning, register-staged dst. rec: {src|ld<<19, w-bits}
__global__ __launch_bounds__(TBIN) void bin_kernel(
        const int* __restrict__ src, const int* __restrict__ dst,
        const float* __restrict__ w, int* __restrict__ binCount,
        uint2* __restrict__ binBuf, int E, int NB) {
    __shared__ int bcnt[256];
    __shared__ int bbase[256];
    for (int i = threadIdx.x; i < 256; i += TBIN) bcnt[i] = 0;
    __syncthreads();

    int base = blockIdx.x * BIN_CHUNK;
    int d[16];
#pragma unroll
    for (int j = 0; j < 16; j++) {
        int e = base + threadIdx.x + j * TBIN;
        d[j] = (e < E) ? dst[e] : -1;
        if (d[j] >= 0) atomicAdd(&bcnt[d[j] >> BSHIFT], 1);
    }
    __syncthreads();
    for (int i = threadIdx.x; i < NB; i += TBIN) {
        int c = bcnt[i];
        bbase[i] = c ? atomicAdd(&binCount[i], c) : 0;
        bcnt[i] = 0;   // reuse as local cursor
    }
    __syncthreads();
#pragma unroll
    for (int j = 0; j < 16; j++) {
        if (d[j] >= 0) {
            int e = base + threadIdx.x + j * TBIN;
            int b = d[j] >> BSHIFT;
            int off = bbase[b] + atomicAdd(&bcnt[b], 1);
            if (off < CAPB) {
                binBuf[(size_t)b * CAPB + off] =
                    make_uint2((unsigned)src[e] | ((unsigned)(d[j] & (BW - 1)) << 19),
                               __float_as_uint(w[e]));
            }
        }
    }
}

// Phase 2: one block per bucket. Count -> scan (8-padded) -> per-node outs ->
// for each 1024-node half: LDS counting-sort index, then coalesced payload
// stream-out (pads = 0 records).
__global__ __launch_bounds__(TBLD) void build_kernel(
        const int* __restrict__ binCount, const uint2* __restrict__ binBuf,
        unsigned* __restrict__ payload, int* __restrict__ seg,
        float* __restrict__ dinv2, float* __restrict__ rdinv,
        const float* __restrict__ x, __half2* __restrict__ z0,
        int N, int NB) {
    __shared__ int   cnt[BW];
    __shared__ float wsum[BW];
    __shared__ int   start[BW];
    __shared__ unsigned short ord[HALF_CAP];
    __shared__ int   tmp[TBLD];
    __shared__ int   stot;
    int b = blockIdx.x;
    int nBase = b << BSHIFT;
    int nCount = min(BW, N - nBase);
    int m = min(binCount[b], CAPB);

    for (int i = threadIdx.x; i < BW; i += TBLD) { cnt[i] = 0; wsum[i] = 0.0f; }
    __syncthreads();

    const uint2* recs = binBuf + (size_t)b * CAPB;
    for (int i = threadIdx.x; i < m; i += TBLD) {
        uint2 r = recs[i];
        int ld = r.x >> 19;
        atomicAdd(&cnt[ld], 1);
        atomicAdd(&wsum[ld], __uint_as_float(r.y));
    }
    __syncthreads();

    // exclusive scan of 8-padded counts, 2 elems/thread
    int b2i = threadIdx.x * 2;
    int c0 = (cnt[b2i] + 7) & ~7;
    int c1 = (cnt[b2i + 1] + 7) & ~7;
    int s = c0 + c1;
    tmp[threadIdx.x] = s;
    __syncthreads();
    for (int off = 1; off < TBLD; off <<= 1) {
        int t = (threadIdx.x >= off) ? tmp[threadIdx.x - off] : 0;
        __syncthreads();
        tmp[threadIdx.x] += t;
        __syncthreads();
    }
    int run = tmp[threadIdx.x] - s;
    start[b2i] = run;
    start[b2i + 1] = run + c0;
    if (threadIdx.x == TBLD - 1) stot = run + s;   // total padded size
    __syncthreads();

    int tot = min(stot, CAP);
    int mid = (nCount > 1024) ? min(start[1024], CAP) : tot;

    // per-node outputs
    for (int i = threadIdx.x; i < nCount; i += TBLD) {
        int n = nBase + i;
        int cc = cnt[i];
        int st = start[i];
        int ng = (cc + 7) >> 3;
        if (st >= CAP) { ng = 0; }
        else if (st + 8 * ng > CAP) { ng = (CAP - st) >> 3; }
        seg[n] = (st >> 3) | (ng << 16);
        float dsum = wsum[i];
        float di = (dsum > 0.0f) ? rsqrtf(dsum) : 0.0f;
        dinv2[n] = di * di;
        rdinv[n] = dsum * di;            // sqrt(deg), 0 if deg==0
        float2 xv = reinterpret_cast<const float2*>(x)[n];
        z0[n] = __float22half2_rn(make_float2(di * xv.x, di * xv.y));
    }
    __syncthreads();

    size_t pbase = (size_t)b * CAP;
    for (int half = 0; half < 2; half++) {
        int lo = half << 10, hi = lo + 1024;
        int pbeg = half ? mid : 0;
        int pend = half ? tot : mid;
        int limit = pend - pbeg;
        int limc = min(limit, HALF_CAP);

        // cursors (reuse cnt) + ord init
        for (int i = lo + threadIdx.x; i < hi; i += TBLD) cnt[i] = start[i] - pbeg;
        for (int j = threadIdx.x; j < limc; j += TBLD) ord[j] = 0xFFFF;
        __syncthreads();

        // counting-sort index pass
        for (int i = threadIdx.x; i < m; i += TBLD) {
            uint2 r = recs[i];
            int ld = r.x >> 19;
            if (ld >= lo && ld < hi) {
                int pos = atomicAdd(&cnt[ld], 1);
                if ((unsigned)pos < (unsigned)limc) ord[pos] = (unsigned short)i;
            }
        }
        __syncthreads();

        // coalesced stream-out (random reads hit L2-resident recs)
        for (int j = threadIdx.x; j < limc; j += TBLD) {
            unsigned short oi = ord[j];
            unsigned word = 0;
            if (oi != 0xFFFF) {
                uint2 r = recs[oi];
                unsigned q = (unsigned)__float2int_rn(__uint_as_float(r.y) * WQ);
                word = (r.x & 0x7FFFFu) | (q << 19);
            }
            payload[pbase + pbeg + j] = word;
        }
        // guard: zero any positions beyond staging cap (astronomically rare)
        for (int j = limc + threadIdx.x; j < limit; j += TBLD)
            payload[pbase + pbeg + j] = 0;
        __syncthreads();
    }
}

// ---- gather helpers: full groups of 8, payload 16B-aligned, no masks ------

__device__ __forceinline__ void gacc2m(const unsigned* __restrict__ payload,
                                       const __half2* __restrict__ zin,
                                       int beg, int ng, float& ax, float& ay) {
    for (int g = 0; g < ng; g++, beg += 8) {
        uint4 r0 = *reinterpret_cast<const uint4*>(payload + beg);
        uint4 r1 = *reinterpret_cast<const uint4*>(payload + beg + 4);
        unsigned r[8] = {r0.x, r0.y, r0.z, r0.w, r1.x, r1.y, r1.z, r1.w};
        __half2 v[8];
#pragma unroll
        for (int j = 0; j < 8; j++) v[j] = zin[r[j] & 0x7FFFFu];
#pragma unroll
        for (int j = 0; j < 8; j++) {
            float wv = (float)(r[j] >> 19) * (1.0f / WQ);
            float2 f = __half22float2(v[j]);
            ax += wv * f.x;
            ay += wv * f.y;
        }
    }
}

// C=4 (quarter-row); ubase = uin + 4*quarter.
__device__ __forceinline__ void gacc4(const unsigned* __restrict__ payload,
                                      const __half* __restrict__ ubase,
                                      int beg, int ng, float* __restrict__ h) {
    for (int g = 0; g < ng; g++, beg += 8) {
        uint4 r0 = *reinterpret_cast<const uint4*>(payload + beg);
        uint4 r1 = *reinterpret_cast<const uint4*>(payload + beg + 4);
        unsigned r[8] = {r0.x, r0.y, r0.z, r0.w, r1.x, r1.y, r1.z, r1.w};
        float2 a[8];
#pragma unroll
        for (int j = 0; j < 8; j++)
            a[j] = *reinterpret_cast<const float2*>(ubase + 16LL * (int)(r[j] & 0x7FFFFu));
#pragma unroll
        for (int j = 0; j < 8; j++) {
            float wv = (float)(r[j] >> 19) * (1.0f / WQ);
            const __half2* hp = reinterpret_cast<const __half2*>(&a[j]);
            float2 v0 = __half22float2(hp[0]);
            float2 v1 = __half22float2(hp[1]);
            h[0] += wv * v0.x;
            h[1] += wv * v0.y;
            h[2] += wv * v1.x;
            h[3] += wv * v1.y;
        }
    }
}

// ----------------------------------------------------------------------------

// z_k[n] = dinv2[n] * sum w * z_{k-1}[src]   (C=2, fp16 state), k=1..3
__global__ void hop2_kernel(const int* __restrict__ seg, const unsigned* __restrict__ payload,
                            const __half2* __restrict__ zin, const float* __restrict__ dinv2,
                            __half2* __restrict__ zout, int N) {
    int n = blockIdx.x * TB + threadIdx.x;
    if (n >= N) return;
    int sp = seg[n];
    int beg = (n >> BSHIFT) * CAP + ((sp & 0xFFFF) << 3);
    int ng = sp >> 16;
    float ax = 0.0f, ay = 0.0f;
    gacc2m(payload, zin, beg, ng, ax, ay);
    float sc = dinv2[n];
    zout[n] = __float22half2_rn(make_float2(ax * sc, ay * sc));
}

// Fused hop2 k=4 + conv1 epilogue
__global__ void hop2_final_kernel(const int* __restrict__ seg, const unsigned* __restrict__ payload,
                                  const __half2* __restrict__ zbuf,   // z0..z3
                                  const float* __restrict__ x,
                                  const float* __restrict__ rdinv, const float* __restrict__ dinv2,
                                  const float* __restrict__ W1, const float* __restrict__ b1,
                                  __half* __restrict__ g0, __half* __restrict__ u0, int N) {
    __shared__ float Ws[160];
    __shared__ float bs[16];
    for (int i = threadIdx.x; i < 160; i += blockDim.x) Ws[i] = W1[i];
    if (threadIdx.x < 16) bs[threadIdx.x] = b1[threadIdx.x];
    __syncthreads();

    int n = blockIdx.x * TB + threadIdx.x;
    if (n >= N) return;

    int sp = seg[n];
    int beg = (n >> BSHIFT) * CAP + ((sp & 0xFFFF) << 3);
    int ng = sp >> 16;
    const __half2* z3 = zbuf + (size_t)3 * N;
    float ax = 0.0f, ay = 0.0f;
    gacc2m(payload, z3, beg, ng, ax, ay);
    float sc = dinv2[n];
    float rd = rdinv[n];

    float coeff[10];
    {
        float2 v = reinterpret_cast<const float2*>(x)[n];
        coeff[0] = v.x; coeff[1] = v.y;
    }
#pragma unroll
    for (int k = 1; k <= 3; k++) {
        float2 v = __half22float2(zbuf[(size_t)k * N + n]);
        coeff[2 * k + 0] = rd * v.x;
        coeff[2 * k + 1] = rd * v.y;
    }
    coeff[8] = rd * sc * ax;
    coeff[9] = rd * sc * ay;

    float o[16];
#pragma unroll
    for (int c = 0; c < 16; c++) o[c] = bs[c];
#pragma unroll
    for (int j = 0; j < 10; j++) {
        float cf = coeff[j];
#pragma unroll
        for (int c = 0; c < 16; c++) o[c] += cf * Ws[j * 16 + c];
    }
#pragma unroll
    for (int c = 0; c < 16; c++) o[c] = fmaxf(o[c], 0.0f);

    float di = sc * rd;   // = dinv (0 for deg-0 nodes)

    __half2 gp[8], up[8];
#pragma unroll
    for (int q = 0; q < 8; q++) {
        gp[q] = __float22half2_rn(make_float2(o[2 * q], o[2 * q + 1]));
        up[q] = __float22half2_rn(make_float2(di * o[2 * q], di * o[2 * q + 1]));
    }
    float4* gw = reinterpret_cast<float4*>(g0 + 16LL * n);
    gw[0] = *reinterpret_cast<float4*>(&gp[0]);
    gw[1] = *reinterpret_cast<float4*>(&gp[4]);
    float4* uw = reinterpret_cast<float4*>(u0 + 16LL * n);
    uw[0] = *reinterpret_cast<float4*>(&up[0]);
    uw[1] = *reinterpret_cast<float4*>(&up[4]);
}

// u_k = dinv2 * sum w * u_{k-1}[src]; 4 threads per node (4 channels each)
__global__ void hop16_kernel(const int* __restrict__ seg, const unsigned* __restrict__ payload,
                             const __half* __restrict__ uin, const float* __restrict__ dinv2,
                             __half* __restrict__ uout, int N) {
    int gid = blockIdx.x * TB + threadIdx.x;
    int n = gid >> 2, quarter = gid & 3;
    if (n >= N) return;
    int sp = seg[n];
    int beg = (n >> BSHIFT) * CAP + ((sp & 0xFFFF) << 3);
    int ng = sp >> 16;

    float h[4] = {0.0f, 0.0f, 0.0f, 0.0f};
    gacc4(payload, uin + 4 * quarter, beg, ng, h);

    float sc = dinv2[n];
    __half2 p[2];
    p[0] = __float22half2_rn(make_float2(h[0] * sc, h[1] * sc));
    p[1] = __float22half2_rn(make_float2(h[2] * sc, h[3] * sc));
    *reinterpret_cast<float2*>(uout + 16LL * n + 4 * quarter) = *reinterpret_cast<float2*>(&p[0]);
}

// Fused hop16 k=4 + conv2 epilogue via MFMA + endLinear + sigmoid.
// Wave = 16 nodes x 4 quads; node=lane&15, quarter=lane>>4.
__global__ void hop16_final_kernel(const int* __restrict__ seg, const unsigned* __restrict__ payload,
                                   const __half* __restrict__ g0, const __half* __restrict__ ubuf,
                                   const float* __restrict__ rdinv, const float* __restrict__ dinv2,
                                   const float* __restrict__ W2, const float* __restrict__ b2,
                                   const float* __restrict__ Wend, float* __restrict__ out, int N) {
    int lane = threadIdx.x & 63;
    int wave = threadIdx.x >> 6;
    int q = lane >> 4;           // quad -> K-chunk
    int nn = lane & 15;          // node row m / output column n
    int node_base = (blockIdx.x * 4 + wave) * 16;
    int node = node_base + nn;
    int nodec = min(node, N - 1);

    // B fragments: lane supplies B[K=32t+8q+i][n=nn] from W2 (fp32->fp16)
    half8 bf[3];
#pragma unroll
    for (int t = 0; t < 3; t++) {
        half8 bv;
#pragma unroll
        for (int i = 0; i < 8; i++) {
            int K = 32 * t + 8 * q + i;
            K = (K < 80) ? K : 79;          // pad rows never used (A=0 there)
            bv[i] = (_Float16)W2[K * 16 + nn];
        }
        bf[t] = bv;
    }
    float bsv = b2[nn];
    float wev = Wend[nn];

    // gather k=4 term: h = quarter q (channels 4q..4q+3) of node's u4 row
    int sp = seg[nodec];
    int beg = (nodec >> BSHIFT) * CAP + ((sp & 0xFFFF) << 3);
    int ng = sp >> 16;
    const __half* u3 = ubuf + (size_t)3 * 16 * N;
    float h[4] = {0.0f, 0.0f, 0.0f, 0.0f};
    gacc4(payload, u3 + 4 * q, beg, ng, h);

    float rd = rdinv[nodec];
    float sc = dinv2[nodec];

    // A fragment t=0: q0,q1 -> g0 (raw); q2,q3 -> u1 (x rd)
    const __half* a0p = ((q < 2) ? g0 : (ubuf + (size_t)16 * N)) + 16LL * nodec + 8 * (q & 1);
    half8 a0 = *reinterpret_cast<const half8*>(a0p);
    a0 = a0 * ((q >= 2) ? (_Float16)rd : (_Float16)1.0f);

    // A fragment t=1: q0,q1 -> u2; q2,q3 -> u3 (all x rd)
    const __half* a1p = ((q < 2) ? (ubuf + (size_t)2 * 16 * N) : (ubuf + (size_t)3 * 16 * N))
                        + 16LL * nodec + 8 * (q & 1);
    half8 a1 = *reinterpret_cast<const half8*>(a1p);
    a1 = a1 * (_Float16)rd;

    // A fragment t=2: q0,q1 -> h (x rd*sc) via shfl repack; q2,q3 -> zero pad
    float s4 = rd * sc;
    __half2 hh0 = __floats2half2_rn(h[0] * s4, h[1] * s4);
    __half2 hh1 = __floats2half2_rn(h[2] * s4, h[3] * s4);
    int p0, p1;
    p0 = *reinterpret_cast<int*>(&hh0);
    p1 = *reinterpret_cast<int*>(&hh1);
    int srcA = (nn + (q << 5)) & 63;   // q0: quarters 0,1 ; q1: quarters 2,3
    int srcB = (srcA + 16) & 63;
    int lo0 = __shfl(p0, srcA, 64);
    int lo1 = __shfl(p1, srcA, 64);
    int hi0 = __shfl(p0, srcB, 64);
    int hi1 = __shfl(p1, srcB, 64);
    if (q >= 2) { lo0 = 0; lo1 = 0; hi0 = 0; hi1 = 0; }
    union { half8 v; int u[4]; } a2;
    a2.u[0] = lo0; a2.u[1] = lo1; a2.u[2] = hi0; a2.u[3] = hi1;

    floatx4 acc = {bsv, bsv, bsv, bsv};
    acc = __builtin_amdgcn_mfma_f32_16x16x32_f16(a0, bf[0], acc, 0, 0, 0);
    acc = __builtin_amdgcn_mfma_f32_16x16x32_f16(a1, bf[1], acc, 0, 0, 0);
    acc = __builtin_amdgcn_mfma_f32_16x16x32_f16(a2.v, bf[2], acc, 0, 0, 0);

    // D[m = q*4+reg][n = nn]: relu, dot with Wend over n, sigmoid, store
    float svals[4];
#pragma unroll
    for (int r = 0; r < 4; r++) {
        float o = fmaxf(acc[r], 0.0f) * wev;
        o += __shfl_xor(o, 1, 64);
        o += __shfl_xor(o, 2, 64);
        o += __shfl_xor(o, 4, 64);
        o += __shfl_xor(o, 8, 64);
        svals[r] = o;
    }
    if (nn == 0) {
#pragma unroll
        for (int r = 0; r < 4; r++) {
            int on = node_base + q * 4 + r;
            if (on < N) out[on] = 1.0f / (1.0f + __expf(-svals[r]));
        }
    }
}

extern "C" void kernel_launch(void* const* d_in, const int* in_sizes, int n_in,
                              void* d_out, int out_size, void* d_ws, size_t ws_size,
                              hipStream_t stream) {
    const float* x    = (const float*)d_in[0];
    const int*   ei   = (const int*)d_in[1];
    const float* w    = (const float*)d_in[2];
    const float* W1   = (const float*)d_in[3];
    const float* b1   = (const float*)d_in[4];
    const float* W2   = (const float*)d_in[5];
    const float* b2   = (const float*)d_in[6];
    const float* Wend = (const float*)d_in[7];
    float* out = (float*)d_out;

    const int N = in_sizes[0] / 2;   // 500000
    const int E = in_sizes[2];       // 4000000
    const int NB = (N + BW - 1) / BW;  // 245

    const int* src = ei;
    const int* dst = ei + E;

    // workspace layout: binCount 4KB | payload 26.1MB | seg 2MB | dinv2 2MB |
    // rdinv 2MB | zbuf 8MB (z0..z3) | g0 16MB | ubuf 64MB (u0..u3);
    // binBuf (34.1MB) aliased over u1..u3 (48MB; dead after build)
    int*      binCount = (int*)d_ws;
    unsigned* payload  = (unsigned*)(binCount + 1024);
    int*      seg      = (int*)(payload + (size_t)NB * CAP);
    float*    dinv2    = (float*)(seg + N);
    float*    rdinv    = dinv2 + N;
    __half2*  zbuf     = (__half2*)(rdinv + N);
    __half*   g0       = (__half*)(zbuf + (size_t)4 * N);
    __half*   ubuf     = g0 + (size_t)16 * N;
    uint2*    binBuf   = (uint2*)(ubuf + (size_t)16 * N);   // over u1..u3

    const int gE_bin = (E + BIN_CHUNK - 1) / BIN_CHUNK;   // 489
    const int gN   = (N + TB - 1) / TB;                   // 1954
    const int gN4  = (4 * N + TB - 1) / TB;               // 7813
    const int gFin = (N + 63) / 64;                       // 7813 (64 nodes/block)

    hipMemsetAsync(binCount, 0, 1024 * sizeof(int), stream);

    // CSR build
    bin_kernel<<<gE_bin, TBIN, 0, stream>>>(src, dst, w, binCount, binBuf, E, NB);
    build_kernel<<<NB, TBLD, 0, stream>>>(binCount, binBuf, payload, seg, dinv2, rdinv, x, zbuf, N, NB);

    // conv1 hops (C=2): z1..z3, then fused z4+epilogue
    for (int k = 1; k <= 3; k++) {
        hop2_kernel<<<gN, TB, 0, stream>>>(seg, payload, zbuf + (size_t)(k - 1) * N,
                                           dinv2, zbuf + (size_t)k * N, N);
    }
    hop2_final_kernel<<<gN, TB, 0, stream>>>(seg, payload, zbuf, x, rdinv, dinv2,
                                             W1, b1, g0, ubuf, N);

    // conv2 hops (C=16): u1..u3 (4 thr/node), then fused u4+MFMA epilogue
    for (int k = 1; k <= 3; k++) {
        hop16_kernel<<<gN4, TB, 0, stream>>>(seg, payload, ubuf + (size_t)(k - 1) * 16 * N,
                                             dinv2, ubuf + (size_t)k * 16 * N, N);
    }
    hop16_final_kernel<<<gFin, TB, 0, stream>>>(seg, payload, g0, ubuf, rdinv, dinv2,
                                                W2, b2, Wend, out, N);
}

// Round 14
// 545.588 us; speedup vs baseline: 1.2359x; 1.0248x over previous
//
#include <hip/hip_runtime.h>
#include <hip/hip_fp16.h>
#include <math.h>

// ---------------------------------------------------------------------------
// TAGConv x2 + linear + sigmoid, 500k nodes / 4M edges.
// Round 14: (a) bin at TBIN=1024 / BIN_CHUNK=16384 (long bucket runs, 16
//           waves/block); (b) paired-group gathers in all hop kernels
//           (16 loads in flight for the dominant ng<=2 cohort).
// Scaled-state propagation z_k = dinv .* h_k (fp16 state); MFMA epilogue;
// LDS counting-sort build (R13).
// ---------------------------------------------------------------------------

#define TB 256
#define TBLD 1024
#define TBIN 1024
#define BSHIFT 11
#define BW 2048             // nodes per bucket
#define CAPB 17408          // binBuf cap (raw recs; mean 16384, ~8 sigma)
#define CAP 26624           // payload cap per bucket (8-padded; mean ~23.6k)
#define HALF_CAP 13312      // ord staging per node-half
#define BIN_CHUNK 16384     // edges per block in bin_kernel
#define WQ 8191.0f          // 13-bit weight quantization

typedef _Float16 half8 __attribute__((ext_vector_type(8)));
typedef float floatx4 __attribute__((ext_vector_type(4)));

// Phase 1: one-pass binning, register-staged dst. rec: {src|ld<<19, w-bits}
__global__ __launch_bounds__(TBIN) void bin_kernel(
        const int* __restrict__ src, const int* __restrict__ dst,
        const float* __restrict__ w, int* __restrict__ binCount,
        uint2* __restrict__ binBuf, int E, int NB) {
    __shared__ int bcnt[256];
    __shared__ int bbase[256];
    for (int i = threadIdx.x; i < 256; i += TBIN) bcnt[i] = 0;
    __syncthreads();

    int base = blockIdx.x * BIN_CHUNK;
    int d[16];
#pragma unroll
    for (int j = 0; j < 16; j++) {
        int e = base + threadIdx.x + j * TBIN;
        d[j] = (e < E) ? dst[e] : -1;
        if (d[j] >= 0) atomicAdd(&bcnt[d[j] >> BSHIFT], 1);
    }
    __syncthreads();
    for (int i = threadIdx.x; i < NB; i += TBIN) {
        int c = bcnt[i];
        bbase[i] = c ? atomicAdd(&binCount[i], c) : 0;
        bcnt[i] = 0;   // reuse as local cursor
    }
    __syncthreads();
#pragma unroll
    for (int j = 0; j < 16; j++) {
        if (d[j] >= 0) {
            int e = base + threadIdx.x + j * TBIN;
            int b = d[j] >> BSHIFT;
            int off = bbase[b] + atomicAdd(&bcnt[b], 1);
            if (off < CAPB) {
                binBuf[(size_t)b * CAPB + off] =
                    make_uint2((unsigned)src[e] | ((unsigned)(d[j] & (BW - 1)) << 19),
                               __float_as_uint(w[e]));
            }
        }
    }
}

// Phase 2: one block per bucket. Count -> scan (8-padded) -> per-node outs ->
// for each 1024-node half: LDS counting-sort index, then coalesced payload
// stream-out (pads = 0 records).
__global__ __launch_bounds__(TBLD) void build_kernel(
        const int* __restrict__ binCount, const uint2* __restrict__ binBuf,
        unsigned* __restrict__ payload, int* __restrict__ seg,
        float* __restrict__ dinv2, float* __restrict__ rdinv,
        const float* __restrict__ x, __half2* __restrict__ z0,
        int N, int NB) {
    __shared__ int   cnt[BW];
    __shared__ float wsum[BW];
    __shared__ int   start[BW];
    __shared__ unsigned short ord[HALF_CAP];
    __shared__ int   tmp[TBLD];
    __shared__ int   stot;
    int b = blockIdx.x;
    int nBase = b << BSHIFT;
    int nCount = min(BW, N - nBase);
    int m = min(binCount[b], CAPB);

    for (int i = threadIdx.x; i < BW; i += TBLD) { cnt[i] = 0; wsum[i] = 0.0f; }
    __syncthreads();

    const uint2* recs = binBuf + (size_t)b * CAPB;
    for (int i = threadIdx.x; i < m; i += TBLD) {
        uint2 r = recs[i];
        int ld = r.x >> 19;
        atomicAdd(&cnt[ld], 1);
        atomicAdd(&wsum[ld], __uint_as_float(r.y));
    }
    __syncthreads();

    // exclusive scan of 8-padded counts, 2 elems/thread
    int b2i = threadIdx.x * 2;
    int c0 = (cnt[b2i] + 7) & ~7;
    int c1 = (cnt[b2i + 1] + 7) & ~7;
    int s = c0 + c1;
    tmp[threadIdx.x] = s;
    __syncthreads();
    for (int off = 1; off < TBLD; off <<= 1) {
        int t = (threadIdx.x >= off) ? tmp[threadIdx.x - off] : 0;
        __syncthreads();
        tmp[threadIdx.x] += t;
        __syncthreads();
    }
    int run = tmp[threadIdx.x] - s;
    start[b2i] = run;
    start[b2i + 1] = run + c0;
    if (threadIdx.x == TBLD - 1) stot = run + s;   // total padded size
    __syncthreads();

    int tot = min(stot, CAP);
    int mid = (nCount > 1024) ? min(start[1024], CAP) : tot;

    // per-node outputs
    for (int i = threadIdx.x; i < nCount; i += TBLD) {
        int n = nBase + i;
        int cc = cnt[i];
        int st = start[i];
        int ng = (cc + 7) >> 3;
        if (st >= CAP) { ng = 0; }
        else if (st + 8 * ng > CAP) { ng = (CAP - st) >> 3; }
        seg[n] = (st >> 3) | (ng << 16);
        float dsum = wsum[i];
        float di = (dsum > 0.0f) ? rsqrtf(dsum) : 0.0f;
        dinv2[n] = di * di;
        rdinv[n] = dsum * di;            // sqrt(deg), 0 if deg==0
        float2 xv = reinterpret_cast<const float2*>(x)[n];
        z0[n] = __float22half2_rn(make_float2(di * xv.x, di * xv.y));
    }
    __syncthreads();

    size_t pbase = (size_t)b * CAP;
    for (int half = 0; half < 2; half++) {
        int lo = half << 10, hi = lo + 1024;
        int pbeg = half ? mid : 0;
        int pend = half ? tot : mid;
        int limit = pend - pbeg;
        int limc = min(limit, HALF_CAP);

        // cursors (reuse cnt) + ord init
        for (int i = lo + threadIdx.x; i < hi; i += TBLD) cnt[i] = start[i] - pbeg;
        for (int j = threadIdx.x; j < limc; j += TBLD) ord[j] = 0xFFFF;
        __syncthreads();

        // counting-sort index pass
        for (int i = threadIdx.x; i < m; i += TBLD) {
            uint2 r = recs[i];
            int ld = r.x >> 19;
            if (ld >= lo && ld < hi) {
                int pos = atomicAdd(&cnt[ld], 1);
                if ((unsigned)pos < (unsigned)limc) ord[pos] = (unsigned short)i;
            }
        }
        __syncthreads();

        // coalesced stream-out (random reads hit L2-resident recs)
        for (int j = threadIdx.x; j < limc; j += TBLD) {
            unsigned short oi = ord[j];
            unsigned word = 0;
            if (oi != 0xFFFF) {
                uint2 r = recs[oi];
                unsigned q = (unsigned)__float2int_rn(__uint_as_float(r.y) * WQ);
                word = (r.x & 0x7FFFFu) | (q << 19);
            }
            payload[pbase + pbeg + j] = word;
        }
        for (int j = limc + threadIdx.x; j < limit; j += TBLD)
            payload[pbase + pbeg + j] = 0;
        __syncthreads();
    }
}

// ---- gather helpers: full groups of 8, paired-group MLP, no masks ---------

// C=2
__device__ __forceinline__ void gacc2m(const unsigned* __restrict__ payload,
                                       const __half2* __restrict__ zin,
                                       int beg, int ng, float& ax, float& ay) {
    int g = 0;
    for (; g + 2 <= ng; g += 2, beg += 16) {
        uint4 r0 = *reinterpret_cast<const uint4*>(payload + beg);
        uint4 r1 = *reinterpret_cast<const uint4*>(payload + beg + 4);
        uint4 r2 = *reinterpret_cast<const uint4*>(payload + beg + 8);
        uint4 r3 = *reinterpret_cast<const uint4*>(payload + beg + 12);
        unsigned r[16] = {r0.x, r0.y, r0.z, r0.w, r1.x, r1.y, r1.z, r1.w,
                          r2.x, r2.y, r2.z, r2.w, r3.x, r3.y, r3.z, r3.w};
        __half2 v[16];
#pragma unroll
        for (int j = 0; j < 16; j++) v[j] = zin[r[j] & 0x7FFFFu];
#pragma unroll
        for (int j = 0; j < 16; j++) {
            float wv = (float)(r[j] >> 19) * (1.0f / WQ);
            float2 f = __half22float2(v[j]);
            ax += wv * f.x;
            ay += wv * f.y;
        }
    }
    if (g < ng) {
        uint4 r0 = *reinterpret_cast<const uint4*>(payload + beg);
        uint4 r1 = *reinterpret_cast<const uint4*>(payload + beg + 4);
        unsigned r[8] = {r0.x, r0.y, r0.z, r0.w, r1.x, r1.y, r1.z, r1.w};
        __half2 v[8];
#pragma unroll
        for (int j = 0; j < 8; j++) v[j] = zin[r[j] & 0x7FFFFu];
#pragma unroll
        for (int j = 0; j < 8; j++) {
            float wv = (float)(r[j] >> 19) * (1.0f / WQ);
            float2 f = __half22float2(v[j]);
            ax += wv * f.x;
            ay += wv * f.y;
        }
    }
}

// C=4 (quarter-row); ubase = uin + 4*quarter.
__device__ __forceinline__ void gacc4(const unsigned* __restrict__ payload,
                                      const __half* __restrict__ ubase,
                                      int beg, int ng, float* __restrict__ h) {
    int g = 0;
    for (; g + 2 <= ng; g += 2, beg += 16) {
        uint4 r0 = *reinterpret_cast<const uint4*>(payload + beg);
        uint4 r1 = *reinterpret_cast<const uint4*>(payload + beg + 4);
        uint4 r2 = *reinterpret_cast<const uint4*>(payload + beg + 8);
        uint4 r3 = *reinterpret_cast<const uint4*>(payload + beg + 12);
        unsigned r[16] = {r0.x, r0.y, r0.z, r0.w, r1.x, r1.y, r1.z, r1.w,
                          r2.x, r2.y, r2.z, r2.w, r3.x, r3.y, r3.z, r3.w};
        float2 a[16];
#pragma unroll
        for (int j = 0; j < 16; j++)
            a[j] = *reinterpret_cast<const float2*>(ubase + 16LL * (int)(r[j] & 0x7FFFFu));
#pragma unroll
        for (int j = 0; j < 16; j++) {
            float wv = (float)(r[j] >> 19) * (1.0f / WQ);
            const __half2* hp = reinterpret_cast<const __half2*>(&a[j]);
            float2 v0 = __half22float2(hp[0]);
            float2 v1 = __half22float2(hp[1]);
            h[0] += wv * v0.x;
            h[1] += wv * v0.y;
            h[2] += wv * v1.x;
            h[3] += wv * v1.y;
        }
    }
    if (g < ng) {
        uint4 r0 = *reinterpret_cast<const uint4*>(payload + beg);
        uint4 r1 = *reinterpret_cast<const uint4*>(payload + beg + 4);
        unsigned r[8] = {r0.x, r0.y, r0.z, r0.w, r1.x, r1.y, r1.z, r1.w};
        float2 a[8];
#pragma unroll
        for (int j = 0; j < 8; j++)
            a[j] = *reinterpret_cast<const float2*>(ubase + 16LL * (int)(r[j] & 0x7FFFFu));
#pragma unroll
        for (int j = 0; j < 8; j++) {
            float wv = (float)(r[j] >> 19) * (1.0f / WQ);
            const __half2* hp = reinterpret_cast<const __half2*>(&a[j]);
            float2 v0 = __half22float2(hp[0]);
            float2 v1 = __half22float2(hp[1]);
            h[0] += wv * v0.x;
            h[1] += wv * v0.y;
            h[2] += wv * v1.x;
            h[3] += wv * v1.y;
        }
    }
}

// ----------------------------------------------------------------------------

// z_k[n] = dinv2[n] * sum w * z_{k-1}[src]   (C=2, fp16 state), k=1..3
__global__ void hop2_kernel(const int* __restrict__ seg, const unsigned* __restrict__ payload,
                            const __half2* __restrict__ zin, const float* __restrict__ dinv2,
                            __half2* __restrict__ zout, int N) {
    int n = blockIdx.x * TB + threadIdx.x;
    if (n >= N) return;
    int sp = seg[n];
    int beg = (n >> BSHIFT) * CAP + ((sp & 0xFFFF) << 3);
    int ng = sp >> 16;
    float ax = 0.0f, ay = 0.0f;
    gacc2m(payload, zin, beg, ng, ax, ay);
    float sc = dinv2[n];
    zout[n] = __float22half2_rn(make_float2(ax * sc, ay * sc));
}

// Fused hop2 k=4 + conv1 epilogue
__global__ void hop2_final_kernel(const int* __restrict__ seg, const unsigned* __restrict__ payload,
                                  const __half2* __restrict__ zbuf,   // z0..z3
                                  const float* __restrict__ x,
                                  const float* __restrict__ rdinv, const float* __restrict__ dinv2,
                                  const float* __restrict__ W1, const float* __restrict__ b1,
                                  __half* __restrict__ g0, __half* __restrict__ u0, int N) {
    __shared__ float Ws[160];
    __shared__ float bs[16];
    for (int i = threadIdx.x; i < 160; i += blockDim.x) Ws[i] = W1[i];
    if (threadIdx.x < 16) bs[threadIdx.x] = b1[threadIdx.x];
    __syncthreads();

    int n = blockIdx.x * TB + threadIdx.x;
    if (n >= N) return;

    int sp = seg[n];
    int beg = (n >> BSHIFT) * CAP + ((sp & 0xFFFF) << 3);
    int ng = sp >> 16;
    const __half2* z3 = zbuf + (size_t)3 * N;
    float ax = 0.0f, ay = 0.0f;
    gacc2m(payload, z3, beg, ng, ax, ay);
    float sc = dinv2[n];
    float rd = rdinv[n];

    float coeff[10];
    {
        float2 v = reinterpret_cast<const float2*>(x)[n];
        coeff[0] = v.x; coeff[1] = v.y;
    }
#pragma unroll
    for (int k = 1; k <= 3; k++) {
        float2 v = __half22float2(zbuf[(size_t)k * N + n]);
        coeff[2 * k + 0] = rd * v.x;
        coeff[2 * k + 1] = rd * v.y;
    }
    coeff[8] = rd * sc * ax;
    coeff[9] = rd * sc * ay;

    float o[16];
#pragma unroll
    for (int c = 0; c < 16; c++) o[c] = bs[c];
#pragma unroll
    for (int j = 0; j < 10; j++) {
        float cf = coeff[j];
#pragma unroll
        for (int c = 0; c < 16; c++) o[c] += cf * Ws[j * 16 + c];
    }
#pragma unroll
    for (int c = 0; c < 16; c++) o[c] = fmaxf(o[c], 0.0f);

    float di = sc * rd;   // = dinv (0 for deg-0 nodes)

    __half2 gp[8], up[8];
#pragma unroll
    for (int q = 0; q < 8; q++) {
        gp[q] = __float22half2_rn(make_float2(o[2 * q], o[2 * q + 1]));
        up[q] = __float22half2_rn(make_float2(di * o[2 * q], di * o[2 * q + 1]));
    }
    float4* gw = reinterpret_cast<float4*>(g0 + 16LL * n);
    gw[0] = *reinterpret_cast<float4*>(&gp[0]);
    gw[1] = *reinterpret_cast<float4*>(&gp[4]);
    float4* uw = reinterpret_cast<float4*>(u0 + 16LL * n);
    uw[0] = *reinterpret_cast<float4*>(&up[0]);
    uw[1] = *reinterpret_cast<float4*>(&up[4]);
}

// u_k = dinv2 * sum w * u_{k-1}[src]; 4 threads per node (4 channels each)
__global__ void hop16_kernel(const int* __restrict__ seg, const unsigned* __restrict__ payload,
                             const __half* __restrict__ uin, const float* __restrict__ dinv2,
                             __half* __restrict__ uout, int N) {
    int gid = blockIdx.x * TB + threadIdx.x;
    int n = gid >> 2, quarter = gid & 3;
    if (n >= N) return;
    int sp = seg[n];
    int beg = (n >> BSHIFT) * CAP + ((sp & 0xFFFF) << 3);
    int ng = sp >> 16;

    float h[4] = {0.0f, 0.0f, 0.0f, 0.0f};
    gacc4(payload, uin + 4 * quarter, beg, ng, h);

    float sc = dinv2[n];
    __half2 p[2];
    p[0] = __float22half2_rn(make_float2(h[0] * sc, h[1] * sc));
    p[1] = __float22half2_rn(make_float2(h[2] * sc, h[3] * sc));
    *reinterpret_cast<float2*>(uout + 16LL * n + 4 * quarter) = *reinterpret_cast<float2*>(&p[0]);
}

// Fused hop16 k=4 + conv2 epilogue via MFMA + endLinear + sigmoid.
// Wave = 16 nodes x 4 quads; node=lane&15, quarter=lane>>4.
__global__ void hop16_final_kernel(const int* __restrict__ seg, const unsigned* __restrict__ payload,
                                   const __half* __restrict__ g0, const __half* __restrict__ ubuf,
                                   const float* __restrict__ rdinv, const float* __restrict__ dinv2,
                                   const float* __restrict__ W2, const float* __restrict__ b2,
                                   const float* __restrict__ Wend, float* __restrict__ out, int N) {
    int lane = threadIdx.x & 63;
    int wave = threadIdx.x >> 6;
    int q = lane >> 4;           // quad -> K-chunk
    int nn = lane & 15;          // node row m / output column n
    int node_base = (blockIdx.x * 4 + wave) * 16;
    int node = node_base + nn;
    int nodec = min(node, N - 1);

    // B fragments: lane supplies B[K=32t+8q+i][n=nn] from W2 (fp32->fp16)
    half8 bf[3];
#pragma unroll
    for (int t = 0; t < 3; t++) {
        half8 bv;
#pragma unroll
        for (int i = 0; i < 8; i++) {
            int K = 32 * t + 8 * q + i;
            K = (K < 80) ? K : 79;          // pad rows never used (A=0 there)
            bv[i] = (_Float16)W2[K * 16 + nn];
        }
        bf[t] = bv;
    }
    float bsv = b2[nn];
    float wev = Wend[nn];

    // gather k=4 term: h = quarter q (channels 4q..4q+3) of node's u4 row
    int sp = seg[nodec];
    int beg = (nodec >> BSHIFT) * CAP + ((sp & 0xFFFF) << 3);
    int ng = sp >> 16;
    const __half* u3 = ubuf + (size_t)3 * 16 * N;
    float h[4] = {0.0f, 0.0f, 0.0f, 0.0f};
    gacc4(payload, u3 + 4 * q, beg, ng, h);

    float rd = rdinv[nodec];
    float sc = dinv2[nodec];

    // A fragment t=0: q0,q1 -> g0 (raw); q2,q3 -> u1 (x rd)
    const __half* a0p = ((q < 2) ? g0 : (ubuf + (size_t)16 * N)) + 16LL * nodec + 8 * (q & 1);
    half8 a0 = *reinterpret_cast<const half8*>(a0p);
    a0 = a0 * ((q >= 2) ? (_Float16)rd : (_Float16)1.0f);

    // A fragment t=1: q0,q1 -> u2; q2,q3 -> u3 (all x rd)
    const __half* a1p = ((q < 2) ? (ubuf + (size_t)2 * 16 * N) : (ubuf + (size_t)3 * 16 * N))
                        + 16LL * nodec + 8 * (q & 1);
    half8 a1 = *reinterpret_cast<const half8*>(a1p);
    a1 = a1 * (_Float16)rd;

    // A fragment t=2: q0,q1 -> h (x rd*sc) via shfl repack; q2,q3 -> zero pad
    float s4 = rd * sc;
    __half2 hh0 = __floats2half2_rn(h[0] * s4, h[1] * s4);
    __half2 hh1 = __floats2half2_rn(h[2] * s4, h[3] * s4);
    int p0, p1;
    p0 = *reinterpret_cast<int*>(&hh0);
    p1 = *reinterpret_cast<int*>(&hh1);
    int srcA = (nn + (q << 5)) & 63;   // q0: quarters 0,1 ; q1: quarters 2,3
    int srcB = (srcA + 16) & 63;
    int lo0 = __shfl(p0, srcA, 64);
    int lo1 = __shfl(p1, srcA, 64);
    int hi0 = __shfl(p0, srcB, 64);
    int hi1 = __shfl(p1, srcB, 64);
    if (q >= 2) { lo0 = 0; lo1 = 0; hi0 = 0; hi1 = 0; }
    union { half8 v; int u[4]; } a2;
    a2.u[0] = lo0; a2.u[1] = lo1; a2.u[2] = hi0; a2.u[3] = hi1;

    floatx4 acc = {bsv, bsv, bsv, bsv};
    acc = __builtin_amdgcn_mfma_f32_16x16x32_f16(a0, bf[0], acc, 0, 0, 0);
    acc = __builtin_amdgcn_mfma_f32_16x16x32_f16(a1, bf[1], acc, 0, 0, 0);
    acc = __builtin_amdgcn_mfma_f32_16x16x32_f16(a2.v, bf[2], acc, 0, 0, 0);

    // D[m = q*4+reg][n = nn]: relu, dot with Wend over n, sigmoid, store
    float svals[4];
#pragma unroll
    for (int r = 0; r < 4; r++) {
        float o = fmaxf(acc[r], 0.0f) * wev;
        o += __shfl_xor(o, 1, 64);
        o += __shfl_xor(o, 2, 64);
        o += __shfl_xor(o, 4, 64);
        o += __shfl_xor(o, 8, 64);
        svals[r] = o;
    }
    if (nn == 0) {
#pragma unroll
        for (int r = 0; r < 4; r++) {
            int on = node_base + q * 4 + r;
            if (on < N) out[on] = 1.0f / (1.0f + __expf(-svals[r]));
        }
    }
}

extern "C" void kernel_launch(void* const* d_in, const int* in_sizes, int n_in,
                              void* d_out, int out_size, void* d_ws, size_t ws_size,
                              hipStream_t stream) {
    const float* x    = (const float*)d_in[0];
    const int*   ei   = (const int*)d_in[1];
    const float* w    = (const float*)d_in[2];
    const float* W1   = (const float*)d_in[3];
    const float* b1   = (const float*)d_in[4];
    const float* W2   = (const float*)d_in[5];
    const float* b2   = (const float*)d_in[6];
    const float* Wend = (const float*)d_in[7];
    float* out = (float*)d_out;

    const int N = in_sizes[0] / 2;   // 500000
    const int E = in_sizes[2];       // 4000000
    const int NB = (N + BW - 1) / BW;  // 245

    const int* src = ei;
    const int* dst = ei + E;

    // workspace layout: binCount 4KB | payload 26.1MB | seg 2MB | dinv2 2MB |
    // rdinv 2MB | zbuf 8MB (z0..z3) | g0 16MB | ubuf 64MB (u0..u3);
    // binBuf (34.1MB) aliased over u1..u3 (48MB; dead after build)
    int*      binCount = (int*)d_ws;
    unsigned* payload  = (unsigned*)(binCount + 1024);
    int*      seg      = (int*)(payload + (size_t)NB * CAP);
    float*    dinv2    = (float*)(seg + N);
    float*    rdinv    = dinv2 + N;
    __half2*  zbuf     = (__half2*)(rdinv + N);
    __half*   g0       = (__half*)(zbuf + (size_t)4 * N);
    __half*   ubuf     = g0 + (size_t)16 * N;
    uint2*    binBuf   = (uint2*)(ubuf + (size_t)16 * N);   // over u1..u3

    const int gE_bin = (E + BIN_CHUNK - 1) / BIN_CHUNK;   // 245
    const int gN   = (N + TB - 1) / TB;                   // 1954
    const int gN4  = (4 * N + TB - 1) / TB;               // 7813
    const int gFin = (N + 63) / 64;                       // 7813 (64 nodes/block)

    hipMemsetAsync(binCount, 0, 1024 * sizeof(int), stream);

    // CSR build
    bin_kernel<<<gE_bin, TBIN, 0, stream>>>(src, dst, w, binCount, binBuf, E, NB);
    build_kernel<<<NB, TBLD, 0, stream>>>(binCount, binBuf, payload, seg, dinv2, rdinv, x, zbuf, N, NB);

    // conv1 hops (C=2): z1..z3, then fused z4+epilogue
    for (int k = 1; k <= 3; k++) {
        hop2_kernel<<<gN, TB, 0, stream>>>(seg, payload, zbuf + (size_t)(k - 1) * N,
                                           dinv2, zbuf + (size_t)k * N, N);
    }
    hop2_final_kernel<<<gN, TB, 0, stream>>>(seg, payload, zbuf, x, rdinv, dinv2,
                                             W1, b1, g0, ubuf, N);

    // conv2 hops (C=16): u1..u3 (4 thr/node), then fused u4+MFMA epilogue
    for (int k = 1; k <= 3; k++) {
        hop16_kernel<<<gN4, TB, 0, stream>>>(seg, payload, ubuf + (size_t)(k - 1) * 16 * N,
                                             dinv2, ubuf + (size_t)k * 16 * N, N);
    }
    hop16_final_kernel<<<gFin, TB, 0, stream>>>(seg, payload, g0, ubuf, rdinv, dinv2,
                                                W2, b2, Wend, out, N);
}